// Round 2
// baseline (1124.659 us; speedup 1.0000x reference)
//
#include <hip/hip_runtime.h>
#include <math.h>

// Problem constants
#define SB 4        // batch
#define SS 2048     // sequence
#define SD 768      // model dim
#define MTOT (SB*SS)

constexpr int BM = 128, BN = 128, BK = 16, PAD = 4;

static_assert(MTOT % BM == 0, "");
static_assert(SD % BN == 0 && SD % BK == 0, "");
static_assert(SS % BM == 0 && SS % BN == 0 && SS % BK == 0, "");

// C[m,n] = alpha * sum_k A[m,k]*B[n,k] + bias[n]    (A:[M,K] rm, B:[N,K] rm)
// Per-blockIdx.z strides sA,sB,sC (elements).
__global__ __launch_bounds__(256) void gemm_nt(
    const float* __restrict__ A, const float* __restrict__ B,
    const float* __restrict__ bias, float* __restrict__ C,
    int Mdim, int Ndim, int Kdim, float alpha,
    long long sA, long long sB, long long sC)
{
    __shared__ float As[BK][BM + PAD];
    __shared__ float Bs[BK][BN + PAD];

    const int tid = threadIdx.x;
    const int tx = tid & 15, ty = tid >> 4;
    const long long z = blockIdx.z;
    A += z * sA; B += z * sB; C += z * sC;
    const int m0 = blockIdx.x * BM, n0 = blockIdx.y * BN;

    const int lr  = tid >> 2;        // 0..63
    const int lk4 = (tid & 3) * 4;   // 0,4,8,12

    float acc[8][8];
#pragma unroll
    for (int i = 0; i < 8; i++)
#pragma unroll
        for (int j = 0; j < 8; j++) acc[i][j] = 0.f;

    for (int k0 = 0; k0 < Kdim; k0 += BK) {
#pragma unroll
        for (int h = 0; h < 2; h++) {
            const int r = lr + h * 64;
            const float4 va = *reinterpret_cast<const float4*>(
                &A[(long long)(m0 + r) * Kdim + k0 + lk4]);
            As[lk4 + 0][r] = va.x; As[lk4 + 1][r] = va.y;
            As[lk4 + 2][r] = va.z; As[lk4 + 3][r] = va.w;
            const float4 vb = *reinterpret_cast<const float4*>(
                &B[(long long)(n0 + r) * Kdim + k0 + lk4]);
            Bs[lk4 + 0][r] = vb.x; Bs[lk4 + 1][r] = vb.y;
            Bs[lk4 + 2][r] = vb.z; Bs[lk4 + 3][r] = vb.w;
        }
        __syncthreads();
#pragma unroll
        for (int k = 0; k < BK; k++) {
            float a[8], b[8];
            *reinterpret_cast<float4*>(a)     = *reinterpret_cast<const float4*>(&As[k][ty * 8]);
            *reinterpret_cast<float4*>(a + 4) = *reinterpret_cast<const float4*>(&As[k][ty * 8 + 4]);
            *reinterpret_cast<float4*>(b)     = *reinterpret_cast<const float4*>(&Bs[k][tx * 8]);
            *reinterpret_cast<float4*>(b + 4) = *reinterpret_cast<const float4*>(&Bs[k][tx * 8 + 4]);
#pragma unroll
            for (int i = 0; i < 8; i++)
#pragma unroll
                for (int j = 0; j < 8; j++) acc[i][j] += a[i] * b[j];
        }
        __syncthreads();
    }

    float bvv[8] = {0, 0, 0, 0, 0, 0, 0, 0};
    if (bias != nullptr) {
#pragma unroll
        for (int j = 0; j < 8; j++) bvv[j] = bias[n0 + tx * 8 + j];
    }
#pragma unroll
    for (int i = 0; i < 8; i++) {
        float out[8];
#pragma unroll
        for (int j = 0; j < 8; j++) out[j] = acc[i][j] * alpha + bvv[j];
        float* cp = &C[(long long)(m0 + ty * 8 + i) * Ndim + n0 + tx * 8];
        *reinterpret_cast<float4*>(cp)     = *reinterpret_cast<float4*>(out);
        *reinterpret_cast<float4*>(cp + 4) = *reinterpret_cast<float4*>(out + 4);
    }
}

// C[m,n] = sum_k A[m,k]*B[k,n]   (A:[M,K] rm, B:[K,N] rm)
__global__ __launch_bounds__(256) void gemm_nn(
    const float* __restrict__ A, const float* __restrict__ B,
    float* __restrict__ C, int Mdim, int Ndim, int Kdim,
    long long sA, long long sB, long long sC)
{
    __shared__ float As[BK][BM + PAD];
    __shared__ float Bs[BK][BN + PAD];

    const int tid = threadIdx.x;
    const int tx = tid & 15, ty = tid >> 4;
    const long long z = blockIdx.z;
    A += z * sA; B += z * sB; C += z * sC;
    const int m0 = blockIdx.x * BM, n0 = blockIdx.y * BN;

    const int lr  = tid >> 2;
    const int lk4 = (tid & 3) * 4;
    const int br  = tid >> 5;        // 0..7
    const int bc  = (tid & 31) * 4;  // 0..124

    float acc[8][8];
#pragma unroll
    for (int i = 0; i < 8; i++)
#pragma unroll
        for (int j = 0; j < 8; j++) acc[i][j] = 0.f;

    for (int k0 = 0; k0 < Kdim; k0 += BK) {
#pragma unroll
        for (int h = 0; h < 2; h++) {
            const int r = lr + h * 64;
            const float4 va = *reinterpret_cast<const float4*>(
                &A[(long long)(m0 + r) * Kdim + k0 + lk4]);
            As[lk4 + 0][r] = va.x; As[lk4 + 1][r] = va.y;
            As[lk4 + 2][r] = va.z; As[lk4 + 3][r] = va.w;
            const float4 vb = *reinterpret_cast<const float4*>(
                &B[(long long)(k0 + br + h * 8) * Ndim + n0 + bc]);
            *reinterpret_cast<float4*>(&Bs[br + h * 8][bc]) = vb;
        }
        __syncthreads();
#pragma unroll
        for (int k = 0; k < BK; k++) {
            float a[8], b[8];
            *reinterpret_cast<float4*>(a)     = *reinterpret_cast<const float4*>(&As[k][ty * 8]);
            *reinterpret_cast<float4*>(a + 4) = *reinterpret_cast<const float4*>(&As[k][ty * 8 + 4]);
            *reinterpret_cast<float4*>(b)     = *reinterpret_cast<const float4*>(&Bs[k][tx * 8]);
            *reinterpret_cast<float4*>(b + 4) = *reinterpret_cast<const float4*>(&Bs[k][tx * 8 + 4]);
#pragma unroll
            for (int i = 0; i < 8; i++)
#pragma unroll
                for (int j = 0; j < 8; j++) acc[i][j] += a[i] * b[j];
        }
        __syncthreads();
    }

#pragma unroll
    for (int i = 0; i < 8; i++) {
        float* cp = &C[(long long)(m0 + ty * 8 + i) * Ndim + n0 + tx * 8];
        *reinterpret_cast<float4*>(cp)     = *reinterpret_cast<float4*>(&acc[i][0]);
        *reinterpret_cast<float4*>(cp + 4) = *reinterpret_cast<float4*>(&acc[i][4]);
    }
}

// In-place row softmax. One block (256 thr) per row of length SS=2048.
__global__ __launch_bounds__(256) void softmax_rows(float* __restrict__ P)
{
    const long long row = blockIdx.x;
    float* p = P + row * (long long)SS;
    const int tid = threadIdx.x;

    float v[8];
    *reinterpret_cast<float4*>(v)     = *reinterpret_cast<const float4*>(&p[tid * 8]);
    *reinterpret_cast<float4*>(v + 4) = *reinterpret_cast<const float4*>(&p[tid * 8 + 4]);

    float mx = v[0];
#pragma unroll
    for (int j = 1; j < 8; j++) mx = fmaxf(mx, v[j]);
#pragma unroll
    for (int off = 32; off >= 1; off >>= 1) mx = fmaxf(mx, __shfl_xor(mx, off));

    __shared__ float redm[4], reds[4];
    if ((tid & 63) == 0) redm[tid >> 6] = mx;
    __syncthreads();
    mx = fmaxf(fmaxf(redm[0], redm[1]), fmaxf(redm[2], redm[3]));

    float sum = 0.f;
#pragma unroll
    for (int j = 0; j < 8; j++) { v[j] = __expf(v[j] - mx); sum += v[j]; }
#pragma unroll
    for (int off = 32; off >= 1; off >>= 1) sum += __shfl_xor(sum, off);
    if ((tid & 63) == 0) reds[tid >> 6] = sum;
    __syncthreads();
    sum = reds[0] + reds[1] + reds[2] + reds[3];

    const float inv = 1.f / sum;
#pragma unroll
    for (int j = 0; j < 8; j++) v[j] *= inv;
    *reinterpret_cast<float4*>(&p[tid * 8])     = *reinterpret_cast<float4*>(v);
    *reinterpret_cast<float4*>(&p[tid * 8 + 4]) = *reinterpret_cast<float4*>(v + 4);
}

extern "C" void kernel_launch(void* const* d_in, const int* in_sizes, int n_in,
                              void* d_out, int out_size, void* d_ws, size_t ws_size,
                              hipStream_t stream)
{
    (void)in_sizes; (void)n_in; (void)out_size; (void)ws_size;
    const float* X  = (const float*)d_in[0];
    const float* Wq = (const float*)d_in[1];
    const float* bq = (const float*)d_in[2];
    const float* Wk = (const float*)d_in[3];
    const float* bk = (const float*)d_in[4];
    const float* Wv = (const float*)d_in[5];
    const float* bv = (const float*)d_in[6];
    float* out = (float*)d_out;

    float* ws = (float*)d_ws;
    const long long nQKV = (long long)MTOT * SD;   // 6.29M elems each
    float* Q = ws;
    float* K = Q + nQKV;
    float* V = K + nQKV;
    float* P = V + nQKV;                           // B*S*S = 16.78M elems

    const dim3 blk(256);

    // 1) QKV projections: [8192,768] x [768,768]^T + b
    const dim3 g1(MTOT / BM, SD / BN, 1);
    gemm_nt<<<g1, blk, 0, stream>>>(X, Wq, bq, Q, MTOT, SD, SD, 1.f, 0, 0, 0);
    gemm_nt<<<g1, blk, 0, stream>>>(X, Wk, bk, K, MTOT, SD, SD, 1.f, 0, 0, 0);
    gemm_nt<<<g1, blk, 0, stream>>>(X, Wv, bv, V, MTOT, SD, SD, 1.f, 0, 0, 0);

    // 2) Scores: per-batch Q[2048,768] x K[2048,768]^T * 1/sqrt(D)
    const float scale = 1.f / sqrtf((float)SD);
    const dim3 g2(SS / BM, SS / BN, SB);
    gemm_nt<<<g2, blk, 0, stream>>>(Q, K, nullptr, P, SS, SS, SD, scale,
                                    (long long)SS * SD, (long long)SS * SD,
                                    (long long)SS * SS);

    // 3) Softmax rows (in place)
    softmax_rows<<<dim3(SB * SS), blk, 0, stream>>>(P);

    // 4) Out: per-batch P[2048,2048] x V[2048,768]
    const dim3 g3(SS / BM, SD / BN, SB);
    gemm_nn<<<g3, blk, 0, stream>>>(P, V, out, SS, SD, SS,
                                    (long long)SS * SS, (long long)SS * SD,
                                    (long long)SS * SD);
}